// Round 5
// baseline (471.599 us; speedup 1.0000x reference)
//
#include <hip/hip_runtime.h>
#include <hip/hip_bf16.h>

// Problem constants: B=64, S=512, H=768, L=9
#define NB 64
#define NS 512
#define NH 768
#define NL 9
#define NROWS (NB*NS)          // 32768
#define EMN (NROWS*NL)         // 294912
#define NBLK 2048              // fused-kernel grid

__device__ __forceinline__ float readlane_f(float v, int l) {
    return __int_as_float(__builtin_amdgcn_readlane(__float_as_int(v), l));
}
__device__ __forceinline__ unsigned long long readlane_u64(unsigned long long v, int l) {
    unsigned int lo = (unsigned int)__builtin_amdgcn_readlane((int)(unsigned int)(v & 0xffffffffULL), l);
    unsigned int hi = (unsigned int)__builtin_amdgcn_readlane((int)(unsigned int)(v >> 32), l);
    return ((unsigned long long)hi << 32) | (unsigned long long)lo;
}
// DPP add: x += dpp_move(x, CTRL); out-of-bound source lanes contribute 0.
template <int CTRL>
__device__ __forceinline__ float dpp_add(float x) {
    int t = __builtin_amdgcn_update_dpp(0, __float_as_int(x), CTRL, 0xf, 0xf, false);
    return x + __int_as_float(t);
}
// Canonical gfx9 wave64 sum; total lands in lane 63. Pure VALU (no LDS pipe).
__device__ __forceinline__ float wave_sum_to63(float x) {
    x = dpp_add<0x111>(x);  // row_shr:1
    x = dpp_add<0x112>(x);  // row_shr:2
    x = dpp_add<0x114>(x);  // row_shr:4
    x = dpp_add<0x118>(x);  // row_shr:8  (lane15 of each row = row sum)
    x = dpp_add<0x142>(x);  // row_bcast:15
    x = dpp_add<0x143>(x);  // row_bcast:31 -> lane63 = wave sum
    return x;
}

// ---------------- Fused kernel: emissions GEMM -> device barrier -> DP ----------------
// All 2048 blocks: gemm slice (wave w of block handles rows 4*(4bx+w)..+3).
// Blocks [0,64):   after barrier: wave0 forward -> +logZ/64; wave1 numerator -> -score/64
// Blocks [64,128): after barrier: Viterbi + backtrack + predict/label/correct
__global__ __launch_bounds__(256) void k_fused(const float* __restrict__ hidden,
                                               const float* __restrict__ W,
                                               const float* __restrict__ bias,
                                               const int* __restrict__ label,
                                               const int* __restrict__ mask,
                                               const float* __restrict__ startT,
                                               const float* __restrict__ endT,
                                               const float* __restrict__ trans,
                                               float* __restrict__ em,
                                               unsigned int* __restrict__ ctr,
                                               float* __restrict__ out) {
    __shared__ float s_em[NS * NL];          // 18KB emissions for this batch
    __shared__ float s_v[NS * NL];           // 18KB viterbi value history
    __shared__ unsigned char s_bp[NS * NL];  // 4.6KB backpointers
    __shared__ unsigned char s_path[NS];     // decoded path
    __shared__ int s_mk[NS];                 // mask
    __shared__ float s_T[NL * NL];

    int bx = blockIdx.x;
    int tid = threadIdx.x;
    int lane = tid & 63;

    // ================= phase 1: GEMM slice =================
    {
        int w = bx * 4 + (tid >> 6);         // global wave id, 0..8191
        if (bx == 0 && tid == 0) { out[0] = 0.f; out[1] = 0.f; }
        // preload W: per c-chunk, 36 consecutive floats starting at (4*lane+256c)*9
        float4 Wr[3][9];
        const float4* Wp = (const float4*)W;
#pragma unroll
        for (int c = 0; c < 3; c++) {
            const float4* p = Wp + 9 * lane + 576 * c;
#pragma unroll
            for (int q = 0; q < 9; q++) Wr[c][q] = p[q];
        }
        float bz[NL];
#pragma unroll
        for (int j = 0; j < NL; j++) bz[j] = bias[j];   // uniform -> SGPR

#pragma unroll
        for (int r = 0; r < 4; r++) {
            int row = 4 * w + r;
            const float* hp = hidden + (size_t)row * NH;
            float4 h[3];
#pragma unroll
            for (int c = 0; c < 3; c++) h[c] = *(const float4*)(hp + 4 * lane + 256 * c);
            float acc[NL];
#pragma unroll
            for (int j = 0; j < NL; j++) acc[j] = 0.f;
#pragma unroll
            for (int c = 0; c < 3; c++) {
                const float hv[4] = { h[c].x, h[c].y, h[c].z, h[c].w };
#pragma unroll
                for (int kk = 0; kk < 4; kk++) {
#pragma unroll
                    for (int j = 0; j < NL; j++) {
                        int fl = kk * 9 + j;
                        const float4& wq = Wr[c][fl >> 2];
                        float wv = (fl & 3) == 0 ? wq.x : (fl & 3) == 1 ? wq.y : (fl & 3) == 2 ? wq.z : wq.w;
                        acc[j] = fmaf(hv[kk], wv, acc[j]);
                    }
                }
            }
            float s[NL];
#pragma unroll
            for (int j = 0; j < NL; j++) s[j] = wave_sum_to63(acc[j]);
            if (lane == 63) {
                float* o = em + (size_t)row * NL;
#pragma unroll
                for (int j = 0; j < NL; j++) o[j] = s[j] + bz[j];
            }
        }
    }

    // ================= device barrier =================
    __syncthreads();                          // all waves' stores drained (vmcnt 0)
    if (tid == 0) {
        __threadfence();                      // device-scope release: L2 writeback
        __atomic_fetch_add(ctr, 1u, __ATOMIC_RELEASE);
    }
    if (bx >= 128) return;                    // pure-gemm blocks done

    if (tid == 0) {
        // spin until all 2048 blocks have published their em rows
        long long guard = 0;
        while (__hip_atomic_load(ctr, __ATOMIC_ACQUIRE, __HIP_MEMORY_SCOPE_AGENT) < NBLK) {
            __builtin_amdgcn_s_sleep(2);
            if (++guard > (1LL << 34)) break; // safety valve: fail loud, never hang
        }
        __threadfence();                      // acquire: invalidate stale caches
    }
    __syncthreads();

    // ================= phase 2: DP =================
    int b = bx & 63;
    // ---- common staging (coalesced) ----
    {
        const float4* ef = (const float4*)(em + (size_t)b * NS * NL);
        float4* sf = (float4*)s_em;
        for (int q = tid; q < NS * NL / 4; q += 256) sf[q] = ef[q];
        if (tid < NS / 4) ((int4*)s_mk)[tid] = ((const int4*)(mask + b * NS))[tid];
        if (tid < NL * NL) s_T[tid] = trans[tid];
    }
    __syncthreads();

    if (bx < NB) {
        if (tid < 64) {
            // ---- forward algorithm (linear domain, exact pow2 renorm) ----
            int j9 = tid < NL ? tid : NL - 1;
            float Mcol[NL];
#pragma unroll
            for (int i = 0; i < NL; i++) Mcol[i] = __expf(s_T[i * NL + j9]);
            float a = __expf(startT[j9] + s_em[j9]);
            int eacc = 0;
            float xpre[4]; int mpre[4];
#pragma unroll
            for (int p = 0; p < 4; p++) { xpre[p] = __expf(s_em[(1 + p) * NL + j9]); mpre[p] = s_mk[1 + p]; }
#pragma unroll 4
            for (int t = 1; t < NS; ++t) {
                float xev = xpre[0]; int mv = mpre[0];
                xpre[0] = xpre[1]; xpre[1] = xpre[2]; xpre[2] = xpre[3];
                mpre[0] = mpre[1]; mpre[1] = mpre[2]; mpre[2] = mpre[3];
                int tn = t + 4; tn = tn < NS ? tn : NS - 1;
                xpre[3] = __expf(s_em[tn * NL + j9]); mpre[3] = s_mk[tn];
                float p0 = readlane_f(a, 0) * Mcol[0];
                float p1 = readlane_f(a, 1) * Mcol[1];
                float p2 = readlane_f(a, 2) * Mcol[2];
                float p3 = readlane_f(a, 3) * Mcol[3];
                float p4 = readlane_f(a, 4) * Mcol[4];
                float p5 = readlane_f(a, 5) * Mcol[5];
                float p6 = readlane_f(a, 6) * Mcol[6];
                float p7 = readlane_f(a, 7) * Mcol[7];
                float p8 = readlane_f(a, 8) * Mcol[8];
                float s = (((p0 + p1) + (p2 + p3)) + ((p4 + p5) + (p6 + p7))) + p8;
                float anew = xev * s;
                a = (mv > 0) ? anew : a;
                if ((t & 7) == 0) {
                    float c0 = readlane_f(a, 0), c1 = readlane_f(a, 1), c2 = readlane_f(a, 2);
                    float c3 = readlane_f(a, 3), c4 = readlane_f(a, 4), c5 = readlane_f(a, 5);
                    float c6 = readlane_f(a, 6), c7 = readlane_f(a, 7), c8 = readlane_f(a, 8);
                    float c = (((c0 + c1) + (c2 + c3)) + ((c4 + c5) + (c6 + c7))) + c8;
                    int ex = ((__float_as_int(c) >> 23) & 255) - 127;
                    a = ldexpf(a, -ex);   // exact rescale
                    eacc += ex;
                }
            }
            float z = a * __expf(endT[j9]);
            float c0 = readlane_f(z, 0), c1 = readlane_f(z, 1), c2 = readlane_f(z, 2);
            float c3 = readlane_f(z, 3), c4 = readlane_f(z, 4), c5 = readlane_f(z, 5);
            float c6 = readlane_f(z, 6), c7 = readlane_f(z, 7), c8 = readlane_f(z, 8);
            float c = (((c0 + c1) + (c2 + c3)) + ((c4 + c5) + (c6 + c7))) + c8;
            if (tid == 0) {
                float lz = (float)eacc * 0.6931471805599453f + __logf(c);
                atomicAdd(out, lz * (1.0f / (float)NB));
            }
        } else if (tid < 128) {
            // ---- numerator (gold path score) ----
            const int* lb = label + b * NS;
            int t0 = lane * 8;
            int lab[8]; int mk[8];
#pragma unroll
            for (int r = 0; r < 8; r++) { lab[r] = lb[t0 + r]; mk[r] = s_mk[t0 + r]; }
            if (lane == 0) mk[0] = 1;
            int h = 0, sl = 0;
#pragma unroll
            for (int r = 0; r < 8; r++) { if (mk[r] > 0) { h = 1; sl = lab[r]; } }
#pragma unroll
            for (int d = 1; d < 64; d <<= 1) {
                int ho = __shfl_up(h, d);
                int so = __shfl_up(sl, d);
                if (!h) { h = ho; sl = so; }
            }
            int lg = __shfl(sl, 63);
            int incoming = __shfl_up(sl, 1);
            float sc = 0.f;
            int prevr = (lane == 0) ? lab[0] : incoming;
#pragma unroll
            for (int r = 0; r < 8; r++) {
                int t = t0 + r;
                if (t > 0) {
                    float s = s_T[prevr * NL + lab[r]] + s_em[t * NL + lab[r]];
                    sc += s * (float)mk[r];
                }
                if (mk[r] > 0) prevr = lab[r];
            }
            if (lane == 0) {
                int g0 = lab[0];
                sc += startT[g0] + s_em[g0] + endT[lg];
            }
#pragma unroll
            for (int d = 1; d < 64; d <<= 1) sc += __shfl_xor(sc, d);
            if (lane == 0) atomicAdd(out, -sc * (1.0f / (float)NB));
        }
    } else {
        // ---- Viterbi phase 1: serial value chain (bit-exact; max is order-free,
        //      and fl(max_i(v_i+T_i)+e) == max_i fl((v_i+T_i)+e) by monotonicity) ----
        if (tid < 64) {
            int j9 = tid < NL ? tid : NL - 1;
            float Tcol[NL];
#pragma unroll
            for (int i = 0; i < NL; i++) Tcol[i] = s_T[i * NL + j9];
            float v = startT[j9] + s_em[j9];
            if (tid < NL) s_v[tid] = v;
            float epre[4];
#pragma unroll
            for (int p = 0; p < 4; p++) epre[p] = s_em[(1 + p) * NL + j9];
#pragma unroll 4
            for (int t = 1; t < NS; ++t) {
                float emv = epre[0];
                epre[0] = epre[1]; epre[1] = epre[2]; epre[2] = epre[3];
                int tn = t + 4; tn = tn < NS ? tn : NS - 1;
                epre[3] = s_em[tn * NL + j9];
                float m0 = readlane_f(v, 0) + Tcol[0];
                float m1 = readlane_f(v, 1) + Tcol[1];
                float m2 = readlane_f(v, 2) + Tcol[2];
                float m3 = readlane_f(v, 3) + Tcol[3];
                float m4 = readlane_f(v, 4) + Tcol[4];
                float m5 = readlane_f(v, 5) + Tcol[5];
                float m6 = readlane_f(v, 6) + Tcol[6];
                float m7 = readlane_f(v, 7) + Tcol[7];
                float m8 = readlane_f(v, 8) + Tcol[8];
                float M = fmaxf(fmaxf(fmaxf(fmaxf(m0, m1), fmaxf(m2, m3)),
                                      fmaxf(fmaxf(m4, m5), fmaxf(m6, m7))), m8);
                v = M + emv;
                if (tid < NL) s_v[t * NL + tid] = v;
            }
        }
        __syncthreads();
        // ---- phase 2: backpointers, parallel over t (exact ref op order + first-index ties) ----
#pragma unroll
        for (int rep = 0; rep < 2; rep++) {
            int t = 1 + tid + 256 * rep;
            if (t < NS) {
                float vp[NL], emt[NL];
#pragma unroll
                for (int i = 0; i < NL; i++) vp[i] = s_v[(t - 1) * NL + i];
#pragma unroll
                for (int j = 0; j < NL; j++) emt[j] = s_em[t * NL + j];
#pragma unroll
                for (int j = 0; j < NL; j++) {
                    float e = emt[j];
                    float val[NL];
#pragma unroll
                    for (int i = 0; i < NL; i++) val[i] = (vp[i] + s_T[i * NL + j]) + e;
                    bool c01 = val[0] >= val[1]; float m01 = c01 ? val[0] : val[1]; int i01 = c01 ? 0 : 1;
                    bool c23 = val[2] >= val[3]; float m23 = c23 ? val[2] : val[3]; int i23 = c23 ? 2 : 3;
                    bool c45 = val[4] >= val[5]; float m45 = c45 ? val[4] : val[5]; int i45 = c45 ? 4 : 5;
                    bool c67 = val[6] >= val[7]; float m67 = c67 ? val[6] : val[7]; int i67 = c67 ? 6 : 7;
                    bool ca = m01 >= m23; float ma = ca ? m01 : m23; int ia = ca ? i01 : i23;
                    bool cb = m45 >= m67; float mb = cb ? m45 : m67; int ib = cb ? i45 : i67;
                    bool cc = ma >= mb;  float mc = cc ? ma : mb;  int ic = cc ? ia : ib;
                    bool cd = mc >= val[8]; int bi = cd ? ic : 8;
                    s_bp[t * NL + j] = (unsigned char)bi;
                }
            } else if (t == NS) {
                s_bp[0 * NL + tid - 255] = 0;  // unused slot; keep writes defined
            }
        }
        __syncthreads();
        // ---- phase 3: last tag + map-composition backtrack (wave 0) ----
        if (tid < 64) {
            float bb = s_v[(NS - 1) * NL + 0] + endT[0]; int lt = 0;
#pragma unroll
            for (int jj = 1; jj < NL; jj++) {
                float fj = s_v[(NS - 1) * NL + jj] + endT[jj];
                if (fj > bb) { bb = fj; lt = jj; }
            }
            unsigned long long G[8];
#pragma unroll
            for (int r = 0; r < 8; r++) {
                int t0 = (lane * 8 + r) * NL;
                unsigned long long g = 0;
                if (lane == 0 && r == 0) {
                    g = 0x876543210ULL;   // t=0 identity (bp[0] unused)
                } else {
#pragma unroll
                    for (int x = 0; x < NL; x++) g |= (unsigned long long)s_bp[t0 + x] << (4 * x);
                }
                G[r] = g;
            }
            unsigned long long A = 0x876543210ULL;
#pragma unroll
            for (int r = 7; r >= 0; r--) {
                unsigned long long An = 0;
#pragma unroll
                for (int x = 0; x < NL; x++) {
                    int ax = (int)((A >> (4 * x)) & 15ULL);
                    int gv = (int)((G[r] >> (4 * ax)) & 15ULL);
                    An |= (unsigned long long)gv << (4 * x);
                }
                A = An;
            }
            int e = 0; int cur = lt;
            for (int ll = 63; ll >= 0; --ll) {
                if (lane == ll) e = cur;
                unsigned long long Al = readlane_u64(A, ll);
                cur = (int)((Al >> (4 * cur)) & 15ULL);
            }
            unsigned long long pw = 0; int c2 = e;
#pragma unroll
            for (int r = 7; r >= 0; r--) {
                pw |= (unsigned long long)c2 << (8 * r);
                c2 = (int)((G[r] >> (4 * c2)) & 15ULL);
            }
            *(unsigned long long*)(s_path + lane * 8) = pw;
        }
        __syncthreads();
        // ---- finalize: predict/label/correct for this batch ----
        const int* lb = label + b * NS;
        float cnt = 0.f;
#pragma unroll
        for (int q = 0; q < 2; q++) {
            int t = tid + q * 256;
            int idx = b * NS + t;
            int lab = lb[t];
            int p = (int)s_path[t];
            int pred = (lab > 0) ? p : 0;
            out[2 + idx] = (float)pred;
            out[2 + NROWS + idx] = (float)lab;
            cnt += (pred == lab) ? 1.f : 0.f;
        }
#pragma unroll
        for (int d = 1; d < 64; d <<= 1) cnt += __shfl_xor(cnt, d);
        if ((tid & 63) == 0) atomicAdd(out + 1, cnt);
    }
}

extern "C" void kernel_launch(void* const* d_in, const int* in_sizes, int n_in,
                              void* d_out, int out_size, void* d_ws, size_t ws_size,
                              hipStream_t stream) {
    const float* hidden = (const float*)d_in[0];
    const int*   label  = (const int*)d_in[1];
    const int*   mask   = (const int*)d_in[2];
    const float* W      = (const float*)d_in[3];
    const float* bias   = (const float*)d_in[4];
    const float* startT = (const float*)d_in[5];
    const float* endT   = (const float*)d_in[6];
    const float* trans  = (const float*)d_in[7];
    float* out = (float*)d_out;

    float* em = (float*)d_ws;                     // EMN floats
    unsigned int* ctr = (unsigned int*)((float*)d_ws + EMN);

    hipMemsetAsync(ctr, 0, sizeof(unsigned int), stream);
    k_fused<<<NBLK, 256, 0, stream>>>(hidden, W, bias, label, mask,
                                      startT, endT, trans, em, ctr, out);
}

// Round 6
// 214.597 us; speedup vs baseline: 2.1976x; 2.1976x over previous
//
#include <hip/hip_runtime.h>
#include <hip/hip_bf16.h>

// Problem constants: B=64, S=512, H=768, L=9
#define NB 64
#define NS 512
#define NH 768
#define NL 9
#define NROWS (NB*NS)          // 32768
#define EMN (NROWS*NL)         // 294912

__device__ __forceinline__ float readlane_f(float v, int l) {
    return __int_as_float(__builtin_amdgcn_readlane(__float_as_int(v), l));
}
__device__ __forceinline__ unsigned long long readlane_u64(unsigned long long v, int l) {
    unsigned int lo = (unsigned int)__builtin_amdgcn_readlane((int)(unsigned int)(v & 0xffffffffULL), l);
    unsigned int hi = (unsigned int)__builtin_amdgcn_readlane((int)(unsigned int)(v >> 32), l);
    return ((unsigned long long)hi << 32) | (unsigned long long)lo;
}
// DPP add: x += dpp_move(x, CTRL); out-of-bound source lanes contribute 0.
template <int CTRL>
__device__ __forceinline__ float dpp_add(float x) {
    int t = __builtin_amdgcn_update_dpp(0, __float_as_int(x), CTRL, 0xf, 0xf, false);
    return x + __int_as_float(t);
}
// Canonical gfx9 wave64 sum; total lands in lane 63. Pure VALU (no LDS pipe).
__device__ __forceinline__ float wave_sum_to63(float x) {
    x = dpp_add<0x111>(x);  // row_shr:1
    x = dpp_add<0x112>(x);  // row_shr:2
    x = dpp_add<0x114>(x);  // row_shr:4
    x = dpp_add<0x118>(x);  // row_shr:8  (lane15 of each row = row sum)
    x = dpp_add<0x142>(x);  // row_bcast:15
    x = dpp_add<0x143>(x);  // row_bcast:31 -> lane63 = wave sum
    return x;
}

// ---------------- Kernel A: emissions GEMM (K split across waves) ----------------
// 8192 blocks x 256 thr; block handles rows 4bx..4bx+3.
// Wave w owns k-range [192w, 192w+192); lane l owns k in {192w+l+64c, c=0..2}.
// Per-lane W footprint = 27 floats -> stays in VGPRs (the R4 version needed 108
// and the compiler rematerialized W loads inside the loop -> load-bound, ~4x slow).
// hidden loads: 3 scalar dwords/row, perfectly coalesced (256B per wave-instr).
// Reduce: DPP to lane63 per wave, then 4-wave combine via small LDS tile.
__global__ __launch_bounds__(256) void k_gemm(const float* __restrict__ hidden,
                                              const float* __restrict__ W,
                                              const float* __restrict__ bias,
                                              float* __restrict__ em,
                                              float* __restrict__ out) {
    __shared__ float s_part[4][4][NL];   // [wave][row][j]
    int tid = threadIdx.x;
    int lane = tid & 63;
    int w = tid >> 6;
    int bx = blockIdx.x;
    if (bx == 0 && tid == 0) { out[0] = 0.f; out[1] = 0.f; }

    int kbase = 192 * w + lane;          // + 64c, c=0..2
    // preload W: 27 scalars, lane-stride 36B (L2-hot after first blocks)
    float Wv[3][NL];
#pragma unroll
    for (int c = 0; c < 3; c++) {
        const float* wp = W + (size_t)(kbase + 64 * c) * NL;
#pragma unroll
        for (int j = 0; j < NL; j++) Wv[c][j] = wp[j];
    }

#pragma unroll
    for (int r = 0; r < 4; r++) {
        int row = 4 * bx + r;
        const float* hp = hidden + (size_t)row * NH + kbase;
        float h0 = hp[0], h1 = hp[64], h2 = hp[128];
        float acc[NL];
#pragma unroll
        for (int j = 0; j < NL; j++) {
            acc[j] = fmaf(h0, Wv[0][j], fmaf(h1, Wv[1][j], h2 * Wv[2][j]));
        }
#pragma unroll
        for (int j = 0; j < NL; j++) acc[j] = wave_sum_to63(acc[j]);
        if (lane == 63) {
#pragma unroll
            for (int j = 0; j < NL; j++) s_part[w][r][j] = acc[j];
        }
    }
    __syncthreads();
    if (tid < 36) {
        int r = tid / NL, j = tid % NL;
        float v = (s_part[0][r][j] + s_part[1][r][j]) +
                  (s_part[2][r][j] + s_part[3][r][j]) + bias[j];
        em[(size_t)(4 * bx + r) * NL + j] = v;
    }
}

// ---------------- Kernel B: DP + finalize ----------------
// blocks [0,64):   wave0 = forward algorithm -> atomicAdd(loss, +logZ/64)
//                  wave1 = gold-path numerator -> atomicAdd(loss, -score/64)
// blocks [64,128): Viterbi fwd + backpointers + backtrack + predict/label/correct
__global__ __launch_bounds__(256) void k_dp(const float* __restrict__ em,
                                            const int* __restrict__ label,
                                            const int* __restrict__ mask,
                                            const float* __restrict__ startT,
                                            const float* __restrict__ endT,
                                            const float* __restrict__ trans,
                                            float* __restrict__ out) {
    __shared__ float s_em[NS * NL];          // 18KB emissions for this batch
    __shared__ float s_v[NS * NL];           // 18KB viterbi value history
    __shared__ unsigned char s_bp[NS * NL];  // 4.6KB backpointers
    __shared__ unsigned char s_path[NS];     // decoded path
    __shared__ int s_mk[NS];                 // mask
    __shared__ float s_T[NL * NL];

    int bx = blockIdx.x;
    int tid = threadIdx.x;
    int lane = tid & 63;
    int b = bx & 63;

    // ---- common staging (coalesced) ----
    {
        const float4* ef = (const float4*)(em + (size_t)b * NS * NL);
        float4* sf = (float4*)s_em;
        for (int q = tid; q < NS * NL / 4; q += 256) sf[q] = ef[q];
        if (tid < NS / 4) ((int4*)s_mk)[tid] = ((const int4*)(mask + b * NS))[tid];
        if (tid < NL * NL) s_T[tid] = trans[tid];
    }
    __syncthreads();

    if (bx < NB) {
        if (tid < 64) {
            // ---- forward algorithm (linear domain, exact pow2 renorm) ----
            int j9 = tid < NL ? tid : NL - 1;
            float Mcol[NL];
#pragma unroll
            for (int i = 0; i < NL; i++) Mcol[i] = __expf(s_T[i * NL + j9]);
            float a = __expf(startT[j9] + s_em[j9]);
            int eacc = 0;
            float xpre[4]; int mpre[4];
#pragma unroll
            for (int p = 0; p < 4; p++) { xpre[p] = __expf(s_em[(1 + p) * NL + j9]); mpre[p] = s_mk[1 + p]; }
#pragma unroll 4
            for (int t = 1; t < NS; ++t) {
                float xev = xpre[0]; int mv = mpre[0];
                xpre[0] = xpre[1]; xpre[1] = xpre[2]; xpre[2] = xpre[3];
                mpre[0] = mpre[1]; mpre[1] = mpre[2]; mpre[2] = mpre[3];
                int tn = t + 4; tn = tn < NS ? tn : NS - 1;
                xpre[3] = __expf(s_em[tn * NL + j9]); mpre[3] = s_mk[tn];
                float p0 = readlane_f(a, 0) * Mcol[0];
                float p1 = readlane_f(a, 1) * Mcol[1];
                float p2 = readlane_f(a, 2) * Mcol[2];
                float p3 = readlane_f(a, 3) * Mcol[3];
                float p4 = readlane_f(a, 4) * Mcol[4];
                float p5 = readlane_f(a, 5) * Mcol[5];
                float p6 = readlane_f(a, 6) * Mcol[6];
                float p7 = readlane_f(a, 7) * Mcol[7];
                float p8 = readlane_f(a, 8) * Mcol[8];
                float s = (((p0 + p1) + (p2 + p3)) + ((p4 + p5) + (p6 + p7))) + p8;
                float anew = xev * s;
                a = (mv > 0) ? anew : a;
                if ((t & 7) == 0) {
                    float c0 = readlane_f(a, 0), c1 = readlane_f(a, 1), c2 = readlane_f(a, 2);
                    float c3 = readlane_f(a, 3), c4 = readlane_f(a, 4), c5 = readlane_f(a, 5);
                    float c6 = readlane_f(a, 6), c7 = readlane_f(a, 7), c8 = readlane_f(a, 8);
                    float c = (((c0 + c1) + (c2 + c3)) + ((c4 + c5) + (c6 + c7))) + c8;
                    int ex = ((__float_as_int(c) >> 23) & 255) - 127;
                    a = ldexpf(a, -ex);   // exact rescale
                    eacc += ex;
                }
            }
            float z = a * __expf(endT[j9]);
            float c0 = readlane_f(z, 0), c1 = readlane_f(z, 1), c2 = readlane_f(z, 2);
            float c3 = readlane_f(z, 3), c4 = readlane_f(z, 4), c5 = readlane_f(z, 5);
            float c6 = readlane_f(z, 6), c7 = readlane_f(z, 7), c8 = readlane_f(z, 8);
            float c = (((c0 + c1) + (c2 + c3)) + ((c4 + c5) + (c6 + c7))) + c8;
            if (tid == 0) {
                float lz = (float)eacc * 0.6931471805599453f + __logf(c);
                atomicAdd(out, lz * (1.0f / (float)NB));
            }
        } else if (tid < 128) {
            // ---- numerator (gold path score) ----
            const int* lb = label + b * NS;
            int t0 = lane * 8;
            int lab[8]; int mk[8];
#pragma unroll
            for (int r = 0; r < 8; r++) { lab[r] = lb[t0 + r]; mk[r] = s_mk[t0 + r]; }
            if (lane == 0) mk[0] = 1;
            int h = 0, sl = 0;
#pragma unroll
            for (int r = 0; r < 8; r++) { if (mk[r] > 0) { h = 1; sl = lab[r]; } }
#pragma unroll
            for (int d = 1; d < 64; d <<= 1) {
                int ho = __shfl_up(h, d);
                int so = __shfl_up(sl, d);
                if (!h) { h = ho; sl = so; }
            }
            int lg = __shfl(sl, 63);
            int incoming = __shfl_up(sl, 1);
            float sc = 0.f;
            int prevr = (lane == 0) ? lab[0] : incoming;
#pragma unroll
            for (int r = 0; r < 8; r++) {
                int t = t0 + r;
                if (t > 0) {
                    float s = s_T[prevr * NL + lab[r]] + s_em[t * NL + lab[r]];
                    sc += s * (float)mk[r];
                }
                if (mk[r] > 0) prevr = lab[r];
            }
            if (lane == 0) {
                int g0 = lab[0];
                sc += startT[g0] + s_em[g0] + endT[lg];
            }
#pragma unroll
            for (int d = 1; d < 64; d <<= 1) sc += __shfl_xor(sc, d);
            if (lane == 0) atomicAdd(out, -sc * (1.0f / (float)NB));
        }
    } else {
        // ---- Viterbi phase 1: serial value chain (bit-exact; max is order-free,
        //      and fl(max_i(v_i+T_i)+e) == max_i fl((v_i+T_i)+e) by monotonicity) ----
        if (tid < 64) {
            int j9 = tid < NL ? tid : NL - 1;
            float Tcol[NL];
#pragma unroll
            for (int i = 0; i < NL; i++) Tcol[i] = s_T[i * NL + j9];
            float v = startT[j9] + s_em[j9];
            if (tid < NL) s_v[tid] = v;
            float epre[4];
#pragma unroll
            for (int p = 0; p < 4; p++) epre[p] = s_em[(1 + p) * NL + j9];
#pragma unroll 4
            for (int t = 1; t < NS; ++t) {
                float emv = epre[0];
                epre[0] = epre[1]; epre[1] = epre[2]; epre[2] = epre[3];
                int tn = t + 4; tn = tn < NS ? tn : NS - 1;
                epre[3] = s_em[tn * NL + j9];
                float m0 = readlane_f(v, 0) + Tcol[0];
                float m1 = readlane_f(v, 1) + Tcol[1];
                float m2 = readlane_f(v, 2) + Tcol[2];
                float m3 = readlane_f(v, 3) + Tcol[3];
                float m4 = readlane_f(v, 4) + Tcol[4];
                float m5 = readlane_f(v, 5) + Tcol[5];
                float m6 = readlane_f(v, 6) + Tcol[6];
                float m7 = readlane_f(v, 7) + Tcol[7];
                float m8 = readlane_f(v, 8) + Tcol[8];
                float M = fmaxf(fmaxf(fmaxf(fmaxf(m0, m1), fmaxf(m2, m3)),
                                      fmaxf(fmaxf(m4, m5), fmaxf(m6, m7))), m8);
                v = M + emv;
                if (tid < NL) s_v[t * NL + tid] = v;
            }
        }
        __syncthreads();
        // ---- phase 2: backpointers, parallel over t (exact ref op order + first-index ties) ----
#pragma unroll
        for (int rep = 0; rep < 2; rep++) {
            int t = 1 + tid + 256 * rep;
            if (t < NS) {
                float vp[NL], emt[NL];
#pragma unroll
                for (int i = 0; i < NL; i++) vp[i] = s_v[(t - 1) * NL + i];
#pragma unroll
                for (int j = 0; j < NL; j++) emt[j] = s_em[t * NL + j];
#pragma unroll
                for (int j = 0; j < NL; j++) {
                    float e = emt[j];
                    float val[NL];
#pragma unroll
                    for (int i = 0; i < NL; i++) val[i] = (vp[i] + s_T[i * NL + j]) + e;
                    bool c01 = val[0] >= val[1]; float m01 = c01 ? val[0] : val[1]; int i01 = c01 ? 0 : 1;
                    bool c23 = val[2] >= val[3]; float m23 = c23 ? val[2] : val[3]; int i23 = c23 ? 2 : 3;
                    bool c45 = val[4] >= val[5]; float m45 = c45 ? val[4] : val[5]; int i45 = c45 ? 4 : 5;
                    bool c67 = val[6] >= val[7]; float m67 = c67 ? val[6] : val[7]; int i67 = c67 ? 6 : 7;
                    bool ca = m01 >= m23; float ma = ca ? m01 : m23; int ia = ca ? i01 : i23;
                    bool cb = m45 >= m67; float mb = cb ? m45 : m67; int ib = cb ? i45 : i67;
                    bool cc = ma >= mb;  float mc = cc ? ma : mb;  int ic = cc ? ia : ib;
                    bool cd = mc >= val[8]; int bi = cd ? ic : 8;
                    s_bp[t * NL + j] = (unsigned char)bi;
                }
            } else if (t == NS) {
                s_bp[0 * NL + tid - 255] = 0;  // unused slot; keep writes defined
            }
        }
        __syncthreads();
        // ---- phase 3: last tag + map-composition backtrack (wave 0) ----
        if (tid < 64) {
            float bb = s_v[(NS - 1) * NL + 0] + endT[0]; int lt = 0;
#pragma unroll
            for (int jj = 1; jj < NL; jj++) {
                float fj = s_v[(NS - 1) * NL + jj] + endT[jj];
                if (fj > bb) { bb = fj; lt = jj; }
            }
            unsigned long long G[8];
#pragma unroll
            for (int r = 0; r < 8; r++) {
                int t0 = (lane * 8 + r) * NL;
                unsigned long long g = 0;
                if (lane == 0 && r == 0) {
                    g = 0x876543210ULL;   // t=0 identity (bp[0] unused)
                } else {
#pragma unroll
                    for (int x = 0; x < NL; x++) g |= (unsigned long long)s_bp[t0 + x] << (4 * x);
                }
                G[r] = g;
            }
            unsigned long long A = 0x876543210ULL;
#pragma unroll
            for (int r = 7; r >= 0; r--) {
                unsigned long long An = 0;
#pragma unroll
                for (int x = 0; x < NL; x++) {
                    int ax = (int)((A >> (4 * x)) & 15ULL);
                    int gv = (int)((G[r] >> (4 * ax)) & 15ULL);
                    An |= (unsigned long long)gv << (4 * x);
                }
                A = An;
            }
            int e = 0; int cur = lt;
            for (int ll = 63; ll >= 0; --ll) {
                if (lane == ll) e = cur;
                unsigned long long Al = readlane_u64(A, ll);
                cur = (int)((Al >> (4 * cur)) & 15ULL);
            }
            unsigned long long pw = 0; int c2 = e;
#pragma unroll
            for (int r = 7; r >= 0; r--) {
                pw |= (unsigned long long)c2 << (8 * r);
                c2 = (int)((G[r] >> (4 * c2)) & 15ULL);
            }
            *(unsigned long long*)(s_path + lane * 8) = pw;
        }
        __syncthreads();
        // ---- finalize: predict/label/correct for this batch ----
        const int* lb = label + b * NS;
        float cnt = 0.f;
#pragma unroll
        for (int q = 0; q < 2; q++) {
            int t = tid + q * 256;
            int idx = b * NS + t;
            int lab = lb[t];
            int p = (int)s_path[t];
            int pred = (lab > 0) ? p : 0;
            out[2 + idx] = (float)pred;
            out[2 + NROWS + idx] = (float)lab;
            cnt += (pred == lab) ? 1.f : 0.f;
        }
#pragma unroll
        for (int d = 1; d < 64; d <<= 1) cnt += __shfl_xor(cnt, d);
        if ((tid & 63) == 0) atomicAdd(out + 1, cnt);
    }
}

extern "C" void kernel_launch(void* const* d_in, const int* in_sizes, int n_in,
                              void* d_out, int out_size, void* d_ws, size_t ws_size,
                              hipStream_t stream) {
    const float* hidden = (const float*)d_in[0];
    const int*   label  = (const int*)d_in[1];
    const int*   mask   = (const int*)d_in[2];
    const float* W      = (const float*)d_in[3];
    const float* bias   = (const float*)d_in[4];
    const float* startT = (const float*)d_in[5];
    const float* endT   = (const float*)d_in[6];
    const float* trans  = (const float*)d_in[7];
    float* out = (float*)d_out;

    float* em = (float*)d_ws;   // EMN floats

    k_gemm<<<8192, 256, 0, stream>>>(hidden, W, bias, em, out);
    k_dp<<<128, 256, 0, stream>>>(em, label, mask, startT, endT, trans, out);
}